// Round 1
// baseline (332.895 us; speedup 1.0000x reference)
//
#include <hip/hip_runtime.h>

// Problem constants (from reference): B=8, L=4096, D=1024, G=128, d=8
#define PB 8
#define PL 4096
#define PD 1024
#define PG 128
#define SEG 32
#define NSEG (PL / SEG)          // 128
#define NEPS 1e-5f

// d_out layout (flat float32): [y: B*L*D][count: B][mean: B*G][var: B*G]
#define YSZ ((size_t)PB * PL * PD)           // 33554432
#define COUNT_OFF (YSZ)
#define MEAN_OFF (YSZ + PB)
#define VAR_OFF (YSZ + PB + (size_t)PB * PG)

// Chan/Welford merge of aggregate (n,m,M2) with element (n2,m2,s2).
// n==0 start state (m=0,M2=0) is handled naturally: m += (m2-m)*1 = m2.
__device__ __forceinline__ void welford_merge(float& n, float& m, float& M2,
                                              float n2, float m2, float s2) {
    if (n2 == 0.0f) return;
    float nn = n + n2;
    float delta = m2 - m;
    float r = n2 / nn;
    m = fmaf(delta, r, m);
    M2 = M2 + s2 + delta * delta * n * r;
    n = nn;
}

// Kernel 1: per-(b, seg, g) aggregate of SEG steps.
// Block = 256 threads = 128 groups x 2 halves; thread u loads float4 at
// (row)*1024 + u*4 -> block loads one contiguous 4KB step per iteration.
__global__ __launch_bounds__(256) void k_agg(const float* __restrict__ x,
                                             const int* __restrict__ mask,
                                             float* __restrict__ aggN,
                                             float* __restrict__ aggM,
                                             float* __restrict__ aggV) {
    int blk = blockIdx.x;
    int b = blk >> 7;              // / NSEG (NSEG=128)
    int seg = blk & (NSEG - 1);
    int u = threadIdx.x;
    size_t row0 = (size_t)b * PL + (size_t)seg * SEG;
    const float4* xp = (const float4*)x + row0 * (PD / 4) + u;
    const int* mp = mask + b * PL + seg * SEG;

    float n = 0.f, m = 0.f, M2 = 0.f;
    float4 v = xp[0];
#pragma unroll 4
    for (int t = 0; t < SEG; ++t) {
        int tn = (t + 1 < SEG) ? (t + 1) : t;
        float4 vnext = xp[(size_t)tn * (PD / 4)];
        int mk = mp[t];
        float s  = v.x + v.y + v.z + v.w;
        float ss = fmaf(v.x, v.x, fmaf(v.y, v.y, fmaf(v.z, v.z, v.w * v.w)));
        s  += __shfl_xor(s, 1);
        ss += __shfl_xor(ss, 1);
        if (mk) {
            float mu = s * 0.125f;
            float sq = fmaxf(ss - s * s * 0.125f, 0.0f);  // sum (x-mu)^2 over 8
            welford_merge(n, m, M2, 8.0f, mu, sq);
        }
        v = vnext;
    }
    if ((u & 1) == 0) {
        int g = u >> 1;
        int idx = (b * NSEG + seg) * PG + g;
        aggN[idx] = n; aggM[idx] = m; aggV[idx] = M2;
    }
}

// Kernel 2: per-(b,g) sequential scan over NSEG aggregates -> exclusive
// carries; writes final count/mean/var outputs.
__global__ __launch_bounds__(256) void k_scan(const void* __restrict__ prev_count,
                                              const float* __restrict__ prev_mean,
                                              const float* __restrict__ prev_var,
                                              const float* __restrict__ aggN,
                                              const float* __restrict__ aggM,
                                              const float* __restrict__ aggV,
                                              float* __restrict__ carN,
                                              float* __restrict__ carM,
                                              float* __restrict__ carV,
                                              float* __restrict__ out) {
    int tid = blockIdx.x * 256 + threadIdx.x;
    if (tid >= PB * PG) return;
    int b = tid >> 7;              // / PG
    int g = tid & (PG - 1);

    // prev_count is int64 per reference; fall back to int32 if the stored
    // layout is actually int32 (heuristic: int64 read of two packed int32
    // ones gives a huge value).
    const long long* p64 = (const long long*)prev_count;
    const int* p32 = (const int*)prev_count;
    long long pv = p64[b];
    float c = (pv >= 0 && pv < (1LL << 31)) ? (float)pv : (float)p32[b];

    float n = c * 8.0f;
    float m = prev_mean[tid];
    float M2 = prev_var[tid] * n;
    for (int seg = 0; seg < NSEG; ++seg) {
        int idx = (b * NSEG + seg) * PG + g;
        carN[idx] = n; carM[idx] = m; carV[idx] = M2;
        welford_merge(n, m, M2, aggN[idx], aggM[idx], aggV[idx]);
    }
    out[MEAN_OFF + tid] = m;
    out[VAR_OFF + tid] = M2 / n;
    if (g == 0) out[COUNT_OFF + b] = n * 0.125f;   // exact: n = 8*count
}

// Kernel 3: per-(b, seg) sequential walk of SEG steps from the carry,
// computing per-step inclusive stats and writing y. Same thread mapping as K1.
__global__ __launch_bounds__(256) void k_out(const float* __restrict__ x,
                                             const int* __restrict__ mask,
                                             const float* __restrict__ weight,
                                             const float* __restrict__ bias,
                                             const float* __restrict__ carN,
                                             const float* __restrict__ carM,
                                             const float* __restrict__ carV,
                                             float* __restrict__ out) {
    int blk = blockIdx.x;
    int b = blk >> 7;
    int seg = blk & (NSEG - 1);
    int u = threadIdx.x;
    int g = u >> 1;

    int cidx = (b * NSEG + seg) * PG + g;
    float n = carN[cidx];
    float m = carM[cidx];
    float M2 = carV[cidx];

    size_t row0 = (size_t)b * PL + (size_t)seg * SEG;
    const float4* xp = (const float4*)x + row0 * (PD / 4) + u;
    float4* yp = (float4*)out + row0 * (PD / 4) + u;
    const int* mp = mask + b * PL + seg * SEG;

    float4 w4 = ((const float4*)weight)[u];
    float4 b4 = ((const float4*)bias)[u];
    float gx = w4.x + 1.0f, gy = w4.y + 1.0f, gz = w4.z + 1.0f, gw = w4.w + 1.0f;

    float4 v = xp[0];
#pragma unroll 4
    for (int t = 0; t < SEG; ++t) {
        int tn = (t + 1 < SEG) ? (t + 1) : t;
        float4 vnext = xp[(size_t)tn * (PD / 4)];
        int mk = mp[t];
        float s  = v.x + v.y + v.z + v.w;
        float ss = fmaf(v.x, v.x, fmaf(v.y, v.y, fmaf(v.z, v.z, v.w * v.w)));
        s  += __shfl_xor(s, 1);
        ss += __shfl_xor(ss, 1);
        if (mk) {
            float mu = s * 0.125f;
            float sq = fmaxf(ss - s * s * 0.125f, 0.0f);
            welford_merge(n, m, M2, 8.0f, mu, sq);
        }
        float rstd = rsqrtf(M2 / n + NEPS);
        float4 y;
        y.x = fmaf((v.x - m) * rstd, gx, b4.x);
        y.y = fmaf((v.y - m) * rstd, gy, b4.y);
        y.z = fmaf((v.z - m) * rstd, gz, b4.z);
        y.w = fmaf((v.w - m) * rstd, gw, b4.w);
        yp[(size_t)t * (PD / 4)] = y;
        v = vnext;
    }
}

extern "C" void kernel_launch(void* const* d_in, const int* in_sizes, int n_in,
                              void* d_out, int out_size, void* d_ws, size_t ws_size,
                              hipStream_t stream) {
    const float* x          = (const float*)d_in[0];
    const void*  prev_count = d_in[1];
    const float* prev_mean  = (const float*)d_in[2];
    const float* prev_var   = (const float*)d_in[3];
    const float* weight     = (const float*)d_in[4];
    const float* bias       = (const float*)d_in[5];
    const int*   mask       = (const int*)d_in[6];
    float* out = (float*)d_out;
    float* ws  = (float*)d_ws;

    const size_t A = (size_t)PB * NSEG * PG;   // 131072 floats per array
    float* aggN = ws + 0 * A;
    float* aggM = ws + 1 * A;
    float* aggV = ws + 2 * A;
    float* carN = ws + 3 * A;
    float* carM = ws + 4 * A;
    float* carV = ws + 5 * A;   // total 3 MiB of workspace

    hipLaunchKernelGGL(k_agg, dim3(PB * NSEG), dim3(256), 0, stream,
                       x, mask, aggN, aggM, aggV);
    hipLaunchKernelGGL(k_scan, dim3((PB * PG + 255) / 256), dim3(256), 0, stream,
                       prev_count, prev_mean, prev_var,
                       aggN, aggM, aggV, carN, carM, carV, out);
    hipLaunchKernelGGL(k_out, dim3(PB * NSEG), dim3(256), 0, stream,
                       x, mask, weight, bias, carN, carM, carV, out);
}

// Round 2
// 280.286 us; speedup vs baseline: 1.1877x; 1.1877x over previous
//
#include <hip/hip_runtime.h>

// Problem constants (from reference): B=8, L=4096, D=1024, G=128, d=8
#define PB 8
#define PL 4096
#define PD 1024
#define PG 128
#define SEG 32
#define NSEG (PL / SEG)          // 128
#define NEPS 1e-5f

// d_out layout (flat float32): [y: B*L*D][count: B][mean: B*G][var: B*G]
#define YSZ ((size_t)PB * PL * PD)
#define COUNT_OFF (YSZ)
#define MEAN_OFF (YSZ + PB)
#define VAR_OFF (YSZ + PB + (size_t)PB * PG)

// State is raw moments per (b,g): n = #elements, S = sum(x), Q = sum(x^2).
// Merge is pure addition (commutative/associative) -> no divide in any
// loop-carried chain. mean = S/n, var = Q/n - mean^2.

// Kernel 1: per-(b, seg, g) aggregate of SEG steps. Block = 256 threads =
// 128 groups x 2 halves; thread u loads float4 at row*1024 + u*4 so the
// block reads one contiguous 4KB step per t. No ordering constraints ->
// deep unroll, loads fully independent.
__global__ __launch_bounds__(256) void k_agg(const float* __restrict__ x,
                                             const int* __restrict__ mask,
                                             float* __restrict__ aggN,
                                             float* __restrict__ aggS,
                                             float* __restrict__ aggQ) {
    int blk = blockIdx.x;
    int b = blk >> 7;              // / NSEG
    int seg = blk & (NSEG - 1);
    int u = threadIdx.x;
    size_t row0 = (size_t)b * PL + (size_t)seg * SEG;
    const float4* xp = (const float4*)x + row0 * (PD / 4) + u;
    const int* mp = mask + b * PL + seg * SEG;

    float S = 0.f, Q = 0.f, Sb = 0.f, Qb = 0.f, nc = 0.f;
#pragma unroll 8
    for (int t = 0; t < SEG; t += 2) {
        float4 v0 = xp[(size_t)t * (PD / 4)];
        float4 v1 = xp[(size_t)(t + 1) * (PD / 4)];
        float f0 = (float)mp[t];
        float f1 = (float)mp[t + 1];
        nc += f0 + f1;
        S  = fmaf(f0, v0.x + v0.y + v0.z + v0.w, S);
        Q  = fmaf(f0, fmaf(v0.x, v0.x, fmaf(v0.y, v0.y, fmaf(v0.z, v0.z, v0.w * v0.w))), Q);
        Sb = fmaf(f1, v1.x + v1.y + v1.z + v1.w, Sb);
        Qb = fmaf(f1, fmaf(v1.x, v1.x, fmaf(v1.y, v1.y, fmaf(v1.z, v1.z, v1.w * v1.w))), Qb);
    }
    S += Sb; Q += Qb;
    S += __shfl_xor(S, 1);
    Q += __shfl_xor(Q, 1);
    if ((u & 1) == 0) {
        int idx = (b * NSEG + seg) * PG + (u >> 1);
        aggN[idx] = 8.0f * nc;
        aggS[idx] = S;
        aggQ[idx] = Q;
    }
}

// Kernel 2: per-(b,g) exclusive prefix over NSEG segment aggregates, with
// software-pipelined (prefetch-1) loads to hide latency at tiny occupancy.
// Also writes final count/mean/var outputs.
__global__ __launch_bounds__(256) void k_scan(const void* __restrict__ prev_count,
                                              const float* __restrict__ prev_mean,
                                              const float* __restrict__ prev_var,
                                              const float* __restrict__ aggN,
                                              const float* __restrict__ aggS,
                                              const float* __restrict__ aggQ,
                                              float* __restrict__ carN,
                                              float* __restrict__ carS,
                                              float* __restrict__ carQ,
                                              float* __restrict__ out) {
    int tid = blockIdx.x * 256 + threadIdx.x;
    if (tid >= PB * PG) return;
    int b = tid >> 7;
    int g = tid & (PG - 1);

    // prev_count is int64 per reference; int32 fallback heuristic.
    const long long* p64 = (const long long*)prev_count;
    const int* p32 = (const int*)prev_count;
    long long pv = p64[b];
    float c = (pv >= 0 && pv < (1LL << 31)) ? (float)pv : (float)p32[b];

    float n = 8.0f * c;
    float m0 = prev_mean[tid];
    float S = m0 * n;
    float Q = fmaf(m0, m0, prev_var[tid]) * n;   // (var + mean^2) * n

    int idx = b * NSEG * PG + g;
    float an = aggN[idx], aS = aggS[idx], aQ = aggQ[idx];
    for (int seg = 0; seg < NSEG; ++seg) {
        int nidx = idx + PG;
        float bn = 0.f, bS = 0.f, bQ = 0.f;
        if (seg + 1 < NSEG) { bn = aggN[nidx]; bS = aggS[nidx]; bQ = aggQ[nidx]; }
        carN[idx] = n; carS[idx] = S; carQ[idx] = Q;
        n += an; S += aS; Q += aQ;
        an = bn; aS = bS; aQ = bQ;
        idx = nidx;
    }
    float inv = 1.0f / n;
    float mean = S * inv;
    out[MEAN_OFF + tid] = mean;
    out[VAR_OFF + tid] = fmaf(-mean, mean, Q * inv);
    if (g == 0) out[COUNT_OFF + b] = n * 0.125f;   // exact: n = 8*count
}

// Kernel 3: per-(b, seg) ordered walk of SEG steps from the carry. Carried
// chain is 3 independent FMAs; normalization math (rcp/rsq) is off-chain.
__global__ __launch_bounds__(256) void k_out(const float* __restrict__ x,
                                             const int* __restrict__ mask,
                                             const float* __restrict__ weight,
                                             const float* __restrict__ bias,
                                             const float* __restrict__ carN,
                                             const float* __restrict__ carS,
                                             const float* __restrict__ carQ,
                                             float* __restrict__ out) {
    int blk = blockIdx.x;
    int b = blk >> 7;
    int seg = blk & (NSEG - 1);
    int u = threadIdx.x;
    int g = u >> 1;

    int cidx = (b * NSEG + seg) * PG + g;
    float n = carN[cidx];
    float S = carS[cidx];
    float Q = carQ[cidx];

    size_t row0 = (size_t)b * PL + (size_t)seg * SEG;
    const float4* xp = (const float4*)x + row0 * (PD / 4) + u;
    float4* yp = (float4*)out + row0 * (PD / 4) + u;
    const int* mp = mask + b * PL + seg * SEG;

    float4 w4 = ((const float4*)weight)[u];
    float4 b4 = ((const float4*)bias)[u];
    float gx = w4.x + 1.0f, gy = w4.y + 1.0f, gz = w4.z + 1.0f, gw = w4.w + 1.0f;

    float4 v = xp[0];
#pragma unroll 4
    for (int t = 0; t < SEG; ++t) {
        int tn = (t + 1 < SEG) ? (t + 1) : t;
        float4 vnext = xp[(size_t)tn * (PD / 4)];
        float f = (float)mp[t];
        float s  = v.x + v.y + v.z + v.w;
        float ss = fmaf(v.x, v.x, fmaf(v.y, v.y, fmaf(v.z, v.z, v.w * v.w)));
        s  += __shfl_xor(s, 1);
        ss += __shfl_xor(ss, 1);
        n = fmaf(f, 8.0f, n);
        S = fmaf(f, s, S);
        Q = fmaf(f, ss, Q);
        float inv  = __builtin_amdgcn_rcpf(n);
        float mean = S * inv;
        float var  = fmaf(-mean, mean, Q * inv);
        float rstd = __builtin_amdgcn_rsqf(var + NEPS);
        float4 y;
        y.x = fmaf((v.x - mean) * rstd, gx, b4.x);
        y.y = fmaf((v.y - mean) * rstd, gy, b4.y);
        y.z = fmaf((v.z - mean) * rstd, gz, b4.z);
        y.w = fmaf((v.w - mean) * rstd, gw, b4.w);
        yp[(size_t)t * (PD / 4)] = y;
        v = vnext;
    }
}

extern "C" void kernel_launch(void* const* d_in, const int* in_sizes, int n_in,
                              void* d_out, int out_size, void* d_ws, size_t ws_size,
                              hipStream_t stream) {
    const float* x          = (const float*)d_in[0];
    const void*  prev_count = d_in[1];
    const float* prev_mean  = (const float*)d_in[2];
    const float* prev_var   = (const float*)d_in[3];
    const float* weight     = (const float*)d_in[4];
    const float* bias       = (const float*)d_in[5];
    const int*   mask       = (const int*)d_in[6];
    float* out = (float*)d_out;
    float* ws  = (float*)d_ws;

    const size_t A = (size_t)PB * NSEG * PG;   // 131072 floats per array
    float* aggN = ws + 0 * A;
    float* aggS = ws + 1 * A;
    float* aggQ = ws + 2 * A;
    float* carN = ws + 3 * A;
    float* carS = ws + 4 * A;
    float* carQ = ws + 5 * A;   // 3 MiB of workspace total

    hipLaunchKernelGGL(k_agg, dim3(PB * NSEG), dim3(256), 0, stream,
                       x, mask, aggN, aggS, aggQ);
    hipLaunchKernelGGL(k_scan, dim3((PB * PG + 255) / 256), dim3(256), 0, stream,
                       prev_count, prev_mean, prev_var,
                       aggN, aggS, aggQ, carN, carS, carQ, out);
    hipLaunchKernelGGL(k_out, dim3(PB * NSEG), dim3(256), 0, stream,
                       x, mask, weight, bias, carN, carS, carQ, out);
}